// Round 2
// baseline (828.902 us; speedup 1.0000x reference)
//
#include <hip/hip_runtime.h>

#define N_NODES 50000
#define N_EDGES 800000
#define D_IN    256
#define D_OUT   128
#define EPS     1e-9f
#define PAD     88      // LDS k-stride in ushorts: 176B rows, 16B-aligned b128

#define SCATTER_BLOCKS 196   // 196 * 4096 = 802816 >= 800000 edges
#define GEMM_MBLKS     391   // ceil(50000/128)

// bucket scatter: rows grouped 64/bucket; global atomics only per (block,bucket)
#define RPB    64
#define NBUCK  782           // ceil(50000/64)
#define BCAP   1344          // mean 1024 + 10 sigma; overflow ~impossible

typedef __attribute__((ext_vector_type(8))) short bf16x8;   // MFMA A/B frag (4 VGPRs)
typedef __attribute__((ext_vector_type(4))) float floatx4;  // MFMA C/D frag

__device__ __forceinline__ ushort f2bf(float x) {           // RTNE fp32 -> bf16
    unsigned u = __float_as_uint(x);
    u += 0x7fffu + ((u >> 16) & 1u);
    return (ushort)(u >> 16);
}

// ---------------------------------------------------------------------------
// prep_small: (a) gcnt[NBUCK] = 0  (b) Wb[n][k] = bf16 transposed [W0|W1].
// ---------------------------------------------------------------------------
#define WB_BLOCKS  32
__global__ __launch_bounds__(256) void prep_small(
    const float* __restrict__ W0, const float* __restrict__ W1,
    ushort* __restrict__ Wb, int* __restrict__ gcnt)
{
    int bid = blockIdx.x;
    int t   = threadIdx.x;
    if (bid == 0) {
        for (int i = t; i < NBUCK; i += 256) gcnt[i] = 0;
    } else {
        int g  = (bid - 1) * 256 + t;
        int n  = g >> 5;                      // 0..255
        int kq = g & 31;                      // 8-elem k group
        const float* W = (n < 128) ? W0 : W1;
        int nn = n & 127;
        union { ushort us[8]; uint4 v; } tmp;
#pragma unroll
        for (int j = 0; j < 8; ++j)
            tmp.us[j] = f2bf(W[(size_t)(kq * 8 + j) * D_OUT + nn]);
        *(uint4*)&Wb[(size_t)n * D_IN + kq * 8] = tmp.v;
    }
}

// ---------------------------------------------------------------------------
// Fused kernel, BLOCK-role split.
//   bid < SCATTER_BLOCKS: LDS-aggregated bucket scatter of 4096 edges.
//     Per-edge rank via LDS atomicAdd on hist[NBUCK]; ONE global atomicAdd per
//     touched (block,bucket) reserves a contiguous range (~152K total global
//     atomics, hidden under the co-running GEMM blocks). Edge packed as
//     (rowlow6<<16 | col16, val) into bedge[bucket][pos].
//   else: 128x128 bf16 MFMA gemm tile, BK=64, 4 waves (unchanged this round).
//     half 0: cols 0..127  -> bias0+relu+LN -> out[:, 0:128]
//     half 1: cols 128..255 -> raw bf16 -> Y1[M,128]
// ---------------------------------------------------------------------------
__global__ __launch_bounds__(256, 3) void gemm_scatter(
    const float* __restrict__ feat, const ushort* __restrict__ Wb,
    const float* __restrict__ bias, const float* __restrict__ scale,
    const float* __restrict__ offset,
    float* __restrict__ out, ushort* __restrict__ Y1,
    const int* __restrict__ er, const int* __restrict__ ec,
    const float* __restrict__ ev, int* __restrict__ gcnt,
    uint2* __restrict__ bedge)
{
    __shared__ ushort As[128 * PAD];
    __shared__ ushort Bs[128 * PAD];

    const int t = threadIdx.x;

    if (blockIdx.x < SCATTER_BLOCKS) {
        int* hist = (int*)As;     // NBUCK ints (3.1KB, fits in 45KB)
        int* base = (int*)Bs;     // NBUCK ints
        for (int i = t; i < NBUCK; i += 256) hist[i] = 0;
        __syncthreads();

        int ebase = blockIdx.x * 4096;
        int   bkt[16], rnk[16];
        uint2 pk[16];
#pragma unroll
        for (int u = 0; u < 16; ++u) {
            int e = ebase + u * 256 + t;
            bool ok = (e < N_EDGES);
            int   r = ok ? er[e] : 0;
            int   c = ok ? ec[e] : 0;
            float v = ok ? ev[e] : 0.f;
            bkt[u] = ok ? (r >> 6) : -1;
            pk[u]  = make_uint2(((unsigned)(r & 63) << 16) | (unsigned)c,
                                __float_as_uint(v));
            if (ok) rnk[u] = atomicAdd(&hist[r >> 6], 1);   // LDS atomic
        }
        __syncthreads();
        for (int i = t; i < NBUCK; i += 256) {
            int h = hist[i];
            base[i] = h ? atomicAdd(&gcnt[i], h) : 0;       // global atomic
        }
        __syncthreads();
#pragma unroll
        for (int u = 0; u < 16; ++u) {
            if (bkt[u] >= 0) {
                int pos = base[bkt[u]] + rnk[u];
                if (pos < BCAP)
                    bedge[(size_t)bkt[u] * BCAP + pos] = pk[u];
            }
        }
        return;
    }

    const int gbid = blockIdx.x - SCATTER_BLOCKS;       // 0..781
    const int half = gbid / GEMM_MBLKS;                 // 0 or 1
    const int mblk = gbid % GEMM_MBLKS;
    const int wave = t >> 6, lane = t & 63;
    const int quad = lane >> 4, l16 = lane & 15;
    const int m0   = mblk * 128;
    const int n0   = half * 128;

    floatx4 acc[2][8];
#pragma unroll
    for (int mt = 0; mt < 2; ++mt)
#pragma unroll
        for (int nt = 0; nt < 8; ++nt)
            acc[mt][nt] = (floatx4){0.f, 0.f, 0.f, 0.f};

    for (int kt = 0; kt < D_IN; kt += 64) {
        // ---- stage A (128 rows x 64 k), fp32 feat -> bf16 on the fly ----
#pragma unroll
        for (int i = 0; i < 4; ++i) {
            int g = t + i * 256;          // 0..1023 (8-elem groups)
            int row = g >> 3, kq = g & 7;
            int grow = m0 + row;
            union { ushort us[8]; uint4 v; } tmp;
            tmp.v = make_uint4(0u, 0u, 0u, 0u);
            if (grow < N_NODES) {
                const float* p = &feat[(size_t)grow * D_IN + kt + kq * 8];
                float4 v0 = *(const float4*)p;
                float4 v1 = *(const float4*)(p + 4);
                tmp.us[0] = f2bf(v0.x); tmp.us[1] = f2bf(v0.y);
                tmp.us[2] = f2bf(v0.z); tmp.us[3] = f2bf(v0.w);
                tmp.us[4] = f2bf(v1.x); tmp.us[5] = f2bf(v1.y);
                tmp.us[6] = f2bf(v1.z); tmp.us[7] = f2bf(v1.w);
            }
            *(uint4*)&As[row * PAD + kq * 8] = tmp.v;
        }
        // ---- stage B (128 n-rows x 64 k) from Wb[n][k] ----
#pragma unroll
        for (int i = 0; i < 4; ++i) {
            int g = t + i * 256;
            int row = g >> 3, kq = g & 7;
            *(uint4*)&Bs[row * PAD + kq * 8] =
                *(const uint4*)&Wb[(size_t)(n0 + row) * D_IN + kt + kq * 8];
        }
        __syncthreads();

#pragma unroll
        for (int kk = 0; kk < 64; kk += 32) {
            bf16x8 a[2], b[8];
#pragma unroll
            for (int mt = 0; mt < 2; ++mt)
                a[mt] = *(bf16x8*)&As[(wave * 32 + mt * 16 + l16) * PAD + kk + quad * 8];
#pragma unroll
            for (int nt = 0; nt < 8; ++nt)
                b[nt] = *(bf16x8*)&Bs[(nt * 16 + l16) * PAD + kk + quad * 8];
#pragma unroll
            for (int mt = 0; mt < 2; ++mt)
#pragma unroll
                for (int nt = 0; nt < 8; ++nt)
                    acc[mt][nt] = __builtin_amdgcn_mfma_f32_16x16x32_bf16(
                        a[mt], b[nt], acc[mt][nt], 0, 0, 0);
        }
        __syncthreads();
    }

    if (half == 0) {
        float bb[8], sc[8], of[8];
#pragma unroll
        for (int nt = 0; nt < 8; ++nt) {
            bb[nt] = bias[nt * 16 + l16];
            sc[nt] = scale[nt * 16 + l16];
            of[nt] = offset[nt * 16 + l16];
        }
#pragma unroll
        for (int mt = 0; mt < 2; ++mt)
#pragma unroll
            for (int i = 0; i < 4; ++i) {
                float h[8], s = 0.f, q = 0.f;
#pragma unroll
                for (int nt = 0; nt < 8; ++nt) {
                    h[nt] = fmaxf(acc[mt][nt][i] + bb[nt], 0.f);
                    s += h[nt];
                    q += h[nt] * h[nt];
                }
#pragma unroll
                for (int m = 1; m < 16; m <<= 1) {
                    s += __shfl_xor(s, m);
                    q += __shfl_xor(q, m);
                }
                float mean = s * (1.f / 128.f);
                float inv  = rsqrtf(q * (1.f / 128.f) - mean * mean + EPS);
                int row = m0 + wave * 32 + mt * 16 + quad * 4 + i;
                if (row < N_NODES) {
#pragma unroll
                    for (int nt = 0; nt < 8; ++nt)
                        out[(size_t)row * 256 + nt * 16 + l16] =
                            (h[nt] - mean) * sc[nt] * inv + of[nt];
                }
            }
    } else {
#pragma unroll
        for (int mt = 0; mt < 2; ++mt)
#pragma unroll
            for (int i = 0; i < 4; ++i) {
                int row = m0 + wave * 32 + mt * 16 + quad * 4 + i;
                if (row < N_NODES) {
#pragma unroll
                    for (int nt = 0; nt < 8; ++nt)
                        Y1[(size_t)row * D_OUT + nt * 16 + l16] =
                            f2bf(acc[mt][nt][i]);
                }
            }
    }
}

// ---------------------------------------------------------------------------
// One block per bucket (64 rows, ~1024 edges). NO CSR build: edge-parallel
// direct accumulation into LDS f32 acc[64][128] via ds_add_f32. Each of 8
// waves takes 8 edges/batch (16 indep VMEM chains in flight: 8 metadata +
// 8 coalesced 256B Y-rows), 2 LDS atomics/lane/edge (4-way bank alias,
// ~1.6x, off critical path). Then bias+relu+LN -> out[:, 128:256].
// LDS 32.8KB -> 4 blocks/CU; 782 blocks -> ~3/CU co-resident, 24 waves/CU.
// ---------------------------------------------------------------------------
__global__ __launch_bounds__(512) void spmm_acc_ln(
    const int* __restrict__ gcnt, const uint2* __restrict__ bedge,
    const ushort* __restrict__ Y,
    const float* __restrict__ bias, const float* __restrict__ scale,
    const float* __restrict__ offset, float* __restrict__ out)
{
    __shared__ float acc[RPB][128];

    const int t      = threadIdx.x;
    const int bucket = blockIdx.x;
    const int r0     = bucket * RPB;
    const int nrows  = min(RPB, N_NODES - r0);
    int ne = gcnt[bucket];
    ne = ne < BCAP ? ne : BCAP;

    // zero acc: 8192 floats = 2048 float4, 4 per thread
    float4* az = (float4*)&acc[0][0];
#pragma unroll
    for (int i = 0; i < 4; ++i)
        az[t + i * 512] = make_float4(0.f, 0.f, 0.f, 0.f);
    __syncthreads();

    const int wave = t >> 6, lane = t & 63;
    const size_t base = (size_t)bucket * BCAP;

    for (int j0 = wave * 8; j0 < ne; j0 += 64) {
        int m = ne - j0;                       // >= 1; valid edges this batch
        unsigned yv[8]; float vv[8]; int rr[8];
#pragma unroll
        for (int u = 0; u < 8; ++u) {
            int j = j0 + (u < m ? u : 0);      // clamp: tail re-reads edge j0
            uint2 p = bedge[base + j];
            rr[u] = (int)(p.x >> 16);
            vv[u] = (u < m) ? __uint_as_float(p.y) : 0.f;   // tail weight 0
            int c = (int)(p.x & 0xffffu);
            yv[u] = *(const unsigned*)&Y[(size_t)c * D_OUT + lane * 2];
        }
#pragma unroll
        for (int u = 0; u < 8; ++u) {
            atomicAdd(&acc[rr[u]][lane * 2],
                      vv[u] * __uint_as_float(yv[u] << 16));
            atomicAdd(&acc[rr[u]][lane * 2 + 1],
                      vv[u] * __uint_as_float(yv[u] & 0xffff0000u));
        }
    }
    __syncthreads();

    const int cidx = lane * 2;
    const float b0v = bias[cidx],   b1v = bias[cidx + 1];
    const float s0v = scale[cidx],  s1v = scale[cidx + 1];
    const float o0v = offset[cidx], o1v = offset[cidx + 1];

    for (int ri = wave; ri < nrows; ri += 8) {
        float2 a2 = *(const float2*)&acc[ri][cidx];
        float h0 = fmaxf(a2.x + b0v, 0.f);
        float h1 = fmaxf(a2.y + b1v, 0.f);
        float s = h0 + h1, q = h0 * h0 + h1 * h1;
#pragma unroll
        for (int m = 1; m < 64; m <<= 1) {
            s += __shfl_xor(s, m);
            q += __shfl_xor(q, m);
        }
        float mean = s * (1.f / 128.f);
        float inv  = rsqrtf(q * (1.f / 128.f) - mean * mean + EPS);
        int row = r0 + ri;
        float2 o;
        o.x = (h0 - mean) * s0v * inv + o0v;
        o.y = (h1 - mean) * s1v * inv + o1v;
        *(float2*)&out[(size_t)row * 256 + 128 + cidx] = o;
    }
}

extern "C" void kernel_launch(void* const* d_in, const int* in_sizes, int n_in,
                              void* d_out, int out_size, void* d_ws, size_t ws_size,
                              hipStream_t stream)
{
    const float* feat = (const float*)d_in[0];
    const float* W0   = (const float*)d_in[1];
    const float* b0   = (const float*)d_in[2];
    const float* s0   = (const float*)d_in[3];
    const float* o0   = (const float*)d_in[4];
    const float* W1   = (const float*)d_in[5];
    const float* b1   = (const float*)d_in[6];
    const float* s1   = (const float*)d_in[7];
    const float* o1   = (const float*)d_in[8];
    const int*   er   = (const int*)d_in[9];
    const int*   ec   = (const int*)d_in[10];
    const float* ev   = (const float*)d_in[11];
    float* out = (float*)d_out;

    // workspace layout (16B-aligned offsets), total ~21.3 MB
    char*   wsb   = (char*)d_ws;
    ushort* Wb    = (ushort*)(wsb);                 //    131,072 B
    ushort* Y1    = (ushort*)(wsb + 131072);        // 12,800,000 B
    int*    gcnt  = (int*)   (wsb + 12931072);      //      3,128 B (padded 4K)
    uint2*  bedge = (uint2*) (wsb + 12935168);      //  8,408,064 B

    prep_small<<<1 + WB_BLOCKS, 256, 0, stream>>>(W0, W1, Wb, gcnt);

    gemm_scatter<<<SCATTER_BLOCKS + 2 * GEMM_MBLKS, 256, 0, stream>>>(
        feat, Wb, b0, s0, o0, out, Y1, er, ec, ev, gcnt, bedge);

    spmm_acc_ln<<<NBUCK, 512, 0, stream>>>(
        gcnt, bedge, Y1, b1, s1, o1, out);
}

// Round 3
// 179.167 us; speedup vs baseline: 4.6264x; 4.6264x over previous
//
#include <hip/hip_runtime.h>

#define N_NODES 50000
#define N_EDGES 800000
#define D_IN    256
#define D_OUT   128
#define EPS     1e-9f
#define PAD     88      // LDS k-stride in ushorts: 176B rows, 16B-aligned b128

#define SCATTER_BLOCKS 196   // 196 * 4096 = 802816 >= 800000 edges
#define GEMM_MBLKS     391   // ceil(50000/128)

// bucket scatter: rows grouped 64/bucket; global atomics only per (block,bucket)
#define RPB    64
#define NBUCK  782           // ceil(50000/64)
#define BCAP   1344          // mean 1024 + 10 sigma; overflow ~impossible

typedef __attribute__((ext_vector_type(8))) short bf16x8;   // MFMA A/B frag (4 VGPRs)
typedef __attribute__((ext_vector_type(4))) float floatx4;  // MFMA C/D frag

__device__ __forceinline__ ushort f2bf(float x) {           // RTNE fp32 -> bf16
    unsigned u = __float_as_uint(x);
    u += 0x7fffu + ((u >> 16) & 1u);
    return (ushort)(u >> 16);
}

// ---------------------------------------------------------------------------
// prep_small: (a) gcnt[NBUCK] = 0  (b) Wb[n][k] = bf16 transposed [W0|W1].
// ---------------------------------------------------------------------------
#define WB_BLOCKS  32
__global__ __launch_bounds__(256) void prep_small(
    const float* __restrict__ W0, const float* __restrict__ W1,
    ushort* __restrict__ Wb, int* __restrict__ gcnt)
{
    int bid = blockIdx.x;
    int t   = threadIdx.x;
    if (bid == 0) {
        for (int i = t; i < NBUCK; i += 256) gcnt[i] = 0;
    } else {
        int g  = (bid - 1) * 256 + t;
        int n  = g >> 5;                      // 0..255
        int kq = g & 31;                      // 8-elem k group
        const float* W = (n < 128) ? W0 : W1;
        int nn = n & 127;
        union { ushort us[8]; uint4 v; } tmp;
#pragma unroll
        for (int j = 0; j < 8; ++j)
            tmp.us[j] = f2bf(W[(size_t)(kq * 8 + j) * D_OUT + nn]);
        *(uint4*)&Wb[(size_t)n * D_IN + kq * 8] = tmp.v;
    }
}

// ---------------------------------------------------------------------------
// Fused kernel, BLOCK-role split.
//   bid < SCATTER_BLOCKS: LDS-aggregated bucket scatter of 4096 edges.
//     Per-edge rank via LDS atomicAdd on hist[NBUCK]; ONE global atomicAdd per
//     touched (block,bucket) reserves a contiguous range (~152K total global
//     atomics, hidden under the co-running GEMM blocks). Edge packed as
//     (rowlow6<<16 | col16, val) into bedge[bucket][pos].
//   else: 128x128 bf16 MFMA gemm tile, BK=64, 4 waves.
//     half 0: cols 0..127  -> bias0+relu+LN -> out[:, 0:128]
//     half 1: cols 128..255 -> raw bf16 -> Y1[M,128]
// ---------------------------------------------------------------------------
__global__ __launch_bounds__(256, 3) void gemm_scatter(
    const float* __restrict__ feat, const ushort* __restrict__ Wb,
    const float* __restrict__ bias, const float* __restrict__ scale,
    const float* __restrict__ offset,
    float* __restrict__ out, ushort* __restrict__ Y1,
    const int* __restrict__ er, const int* __restrict__ ec,
    const float* __restrict__ ev, int* __restrict__ gcnt,
    uint2* __restrict__ bedge)
{
    __shared__ ushort As[128 * PAD];
    __shared__ ushort Bs[128 * PAD];

    const int t = threadIdx.x;

    if (blockIdx.x < SCATTER_BLOCKS) {
        int* hist = (int*)As;     // NBUCK ints (3.1KB, fits in 45KB)
        int* base = (int*)Bs;     // NBUCK ints
        for (int i = t; i < NBUCK; i += 256) hist[i] = 0;
        __syncthreads();

        int ebase = blockIdx.x * 4096;
        int   bkt[16], rnk[16];
        uint2 pk[16];
#pragma unroll
        for (int u = 0; u < 16; ++u) {
            int e = ebase + u * 256 + t;
            bool ok = (e < N_EDGES);
            int   r = ok ? er[e] : 0;
            int   c = ok ? ec[e] : 0;
            float v = ok ? ev[e] : 0.f;
            bkt[u] = ok ? (r >> 6) : -1;
            pk[u]  = make_uint2(((unsigned)(r & 63) << 16) | (unsigned)c,
                                __float_as_uint(v));
            if (ok) rnk[u] = atomicAdd(&hist[r >> 6], 1);   // LDS int atomic
        }
        __syncthreads();
        for (int i = t; i < NBUCK; i += 256) {
            int h = hist[i];
            base[i] = h ? atomicAdd(&gcnt[i], h) : 0;       // global atomic
        }
        __syncthreads();
#pragma unroll
        for (int u = 0; u < 16; ++u) {
            if (bkt[u] >= 0) {
                int pos = base[bkt[u]] + rnk[u];
                if (pos < BCAP)
                    bedge[(size_t)bkt[u] * BCAP + pos] = pk[u];
            }
        }
        return;
    }

    const int gbid = blockIdx.x - SCATTER_BLOCKS;       // 0..781
    const int half = gbid / GEMM_MBLKS;                 // 0 or 1
    const int mblk = gbid % GEMM_MBLKS;
    const int wave = t >> 6, lane = t & 63;
    const int quad = lane >> 4, l16 = lane & 15;
    const int m0   = mblk * 128;
    const int n0   = half * 128;

    floatx4 acc[2][8];
#pragma unroll
    for (int mt = 0; mt < 2; ++mt)
#pragma unroll
        for (int nt = 0; nt < 8; ++nt)
            acc[mt][nt] = (floatx4){0.f, 0.f, 0.f, 0.f};

    for (int kt = 0; kt < D_IN; kt += 64) {
        // ---- stage A (128 rows x 64 k), fp32 feat -> bf16 on the fly ----
#pragma unroll
        for (int i = 0; i < 4; ++i) {
            int g = t + i * 256;          // 0..1023 (8-elem groups)
            int row = g >> 3, kq = g & 7;
            int grow = m0 + row;
            union { ushort us[8]; uint4 v; } tmp;
            tmp.v = make_uint4(0u, 0u, 0u, 0u);
            if (grow < N_NODES) {
                const float* p = &feat[(size_t)grow * D_IN + kt + kq * 8];
                float4 v0 = *(const float4*)p;
                float4 v1 = *(const float4*)(p + 4);
                tmp.us[0] = f2bf(v0.x); tmp.us[1] = f2bf(v0.y);
                tmp.us[2] = f2bf(v0.z); tmp.us[3] = f2bf(v0.w);
                tmp.us[4] = f2bf(v1.x); tmp.us[5] = f2bf(v1.y);
                tmp.us[6] = f2bf(v1.z); tmp.us[7] = f2bf(v1.w);
            }
            *(uint4*)&As[row * PAD + kq * 8] = tmp.v;
        }
        // ---- stage B (128 n-rows x 64 k) from Wb[n][k] ----
#pragma unroll
        for (int i = 0; i < 4; ++i) {
            int g = t + i * 256;
            int row = g >> 3, kq = g & 7;
            *(uint4*)&Bs[row * PAD + kq * 8] =
                *(const uint4*)&Wb[(size_t)(n0 + row) * D_IN + kt + kq * 8];
        }
        __syncthreads();

#pragma unroll
        for (int kk = 0; kk < 64; kk += 32) {
            bf16x8 a[2], b[8];
#pragma unroll
            for (int mt = 0; mt < 2; ++mt)
                a[mt] = *(bf16x8*)&As[(wave * 32 + mt * 16 + l16) * PAD + kk + quad * 8];
#pragma unroll
            for (int nt = 0; nt < 8; ++nt)
                b[nt] = *(bf16x8*)&Bs[(nt * 16 + l16) * PAD + kk + quad * 8];
#pragma unroll
            for (int mt = 0; mt < 2; ++mt)
#pragma unroll
                for (int nt = 0; nt < 8; ++nt)
                    acc[mt][nt] = __builtin_amdgcn_mfma_f32_16x16x32_bf16(
                        a[mt], b[nt], acc[mt][nt], 0, 0, 0);
        }
        __syncthreads();
    }

    if (half == 0) {
        float bb[8], sc[8], of[8];
#pragma unroll
        for (int nt = 0; nt < 8; ++nt) {
            bb[nt] = bias[nt * 16 + l16];
            sc[nt] = scale[nt * 16 + l16];
            of[nt] = offset[nt * 16 + l16];
        }
#pragma unroll
        for (int mt = 0; mt < 2; ++mt)
#pragma unroll
            for (int i = 0; i < 4; ++i) {
                float h[8], s = 0.f, q = 0.f;
#pragma unroll
                for (int nt = 0; nt < 8; ++nt) {
                    h[nt] = fmaxf(acc[mt][nt][i] + bb[nt], 0.f);
                    s += h[nt];
                    q += h[nt] * h[nt];
                }
#pragma unroll
                for (int m = 1; m < 16; m <<= 1) {
                    s += __shfl_xor(s, m);
                    q += __shfl_xor(q, m);
                }
                float mean = s * (1.f / 128.f);
                float inv  = rsqrtf(q * (1.f / 128.f) - mean * mean + EPS);
                int row = m0 + wave * 32 + mt * 16 + quad * 4 + i;
                if (row < N_NODES) {
#pragma unroll
                    for (int nt = 0; nt < 8; ++nt)
                        out[(size_t)row * 256 + nt * 16 + l16] =
                            (h[nt] - mean) * sc[nt] * inv + of[nt];
                }
            }
    } else {
#pragma unroll
        for (int mt = 0; mt < 2; ++mt)
#pragma unroll
            for (int i = 0; i < 4; ++i) {
                int row = m0 + wave * 32 + mt * 16 + quad * 4 + i;
                if (row < N_NODES) {
#pragma unroll
                    for (int nt = 0; nt < 8; ++nt)
                        Y1[(size_t)row * D_OUT + nt * 16 + l16] =
                            f2bf(acc[mt][nt][i]);
                }
            }
    }
}

// ---------------------------------------------------------------------------
// One block per bucket (64 rows, ~1024 edges), 512 threads (8 waves).
// ONE-pass CSR build: each thread keeps <=3 edges in NAMED registers
// (no runtime-indexed arrays -> no scratch), LDS int atomics give per-row
// ranks, wave 0 does a 64-wide shfl prefix scan, place from registers.
// Then wave-per-row gather of bf16 Y rows (8-deep ILP) + bias+relu+LN
// -> out[:, 128:256].
// LDS ~8.6KB; 782 blocks -> ~3 blocks/CU x 8 waves = 24 waves/CU.
// ---------------------------------------------------------------------------
__global__ __launch_bounds__(512) void spmm_csr_ln(
    const int* __restrict__ gcnt, const uint2* __restrict__ bedge,
    const ushort* __restrict__ Y,
    const float* __restrict__ bias, const float* __restrict__ scale,
    const float* __restrict__ offset, float* __restrict__ out)
{
    __shared__ ushort lcol[BCAP];
    __shared__ float  lval[BCAP];
    __shared__ int    cnt[RPB];
    __shared__ int    offx[RPB];

    const int t      = threadIdx.x;
    const int bucket = blockIdx.x;
    const int r0     = bucket * RPB;
    const int nrows  = min(RPB, N_NODES - r0);
    int ne = gcnt[bucket];
    ne = ne < BCAP ? ne : BCAP;

    if (t < RPB) cnt[t] = 0;
    __syncthreads();

    // ---- count pass (single bedge read; edges parked in named regs) ----
    const size_t base = (size_t)bucket * BCAP;
    int   erA = -1, erB = -1, erC = -1;
    int   ecA = 0,  ecB = 0,  ecC = 0;
    float evA = 0.f, evB = 0.f, evC = 0.f;
    int   rkA = 0,  rkB = 0,  rkC = 0;
    if (t < ne) {
        uint2 p = bedge[base + t];
        erA = (int)(p.x >> 16); ecA = (int)(p.x & 0xffffu);
        evA = __uint_as_float(p.y);
        rkA = atomicAdd(&cnt[erA], 1);
    }
    if (t + 512 < ne) {
        uint2 p = bedge[base + t + 512];
        erB = (int)(p.x >> 16); ecB = (int)(p.x & 0xffffu);
        evB = __uint_as_float(p.y);
        rkB = atomicAdd(&cnt[erB], 1);
    }
    if (t + 1024 < ne) {
        uint2 p = bedge[base + t + 1024];
        erC = (int)(p.x >> 16); ecC = (int)(p.x & 0xffffu);
        evC = __uint_as_float(p.y);
        rkC = atomicAdd(&cnt[erC], 1);
    }
    __syncthreads();

    // ---- exclusive prefix over 64 counts, wave 0 via shfl ----
    if (t < RPB) {
        int c = cnt[t], x = c;
#pragma unroll
        for (int s = 1; s < RPB; s <<= 1) {
            int w = __shfl_up(x, s);
            if (t >= s) x += w;
        }
        offx[t] = x - c;
    }
    __syncthreads();

    // ---- place from registers ----
    if (erA >= 0) { int k = offx[erA] + rkA; lcol[k] = (ushort)ecA; lval[k] = evA; }
    if (erB >= 0) { int k = offx[erB] + rkB; lcol[k] = (ushort)ecB; lval[k] = evB; }
    if (erC >= 0) { int k = offx[erC] + rkC; lcol[k] = (ushort)ecC; lval[k] = evC; }
    __syncthreads();

    // ---- wave-per-row gather + LN ----
    const int wave = t >> 6, lane = t & 63;
    const int cidx = lane * 2;
    const float b0v = bias[cidx],   b1v = bias[cidx + 1];
    const float s0v = scale[cidx],  s1v = scale[cidx + 1];
    const float o0v = offset[cidx], o1v = offset[cidx + 1];

    for (int ri = wave; ri < nrows; ri += 8) {
        int beg = offx[ri], n = cnt[ri];
        float ax = 0.f, ay = 0.f;
        int j = 0;
        for (; j + 8 <= n; j += 8) {
            unsigned yv[8]; float vv[8]; int cc[8];
#pragma unroll
            for (int u = 0; u < 8; ++u) {
                cc[u] = lcol[beg + j + u];             // LDS broadcast
                vv[u] = lval[beg + j + u];
                yv[u] = *(const unsigned*)&Y[(size_t)cc[u] * D_OUT + cidx];
            }
#pragma unroll
            for (int u = 0; u < 8; ++u) {
                ax = fmaf(vv[u], __uint_as_float(yv[u] << 16), ax);
                ay = fmaf(vv[u], __uint_as_float(yv[u] & 0xffff0000u), ay);
            }
        }
        for (; j < n; ++j) {
            int   c  = lcol[beg + j];
            float vj = lval[beg + j];
            unsigned yv = *(const unsigned*)&Y[(size_t)c * D_OUT + cidx];
            ax = fmaf(vj, __uint_as_float(yv << 16), ax);
            ay = fmaf(vj, __uint_as_float(yv & 0xffff0000u), ay);
        }
        float h0 = fmaxf(ax + b0v, 0.f);
        float h1 = fmaxf(ay + b1v, 0.f);
        float s = h0 + h1, q = h0 * h0 + h1 * h1;
#pragma unroll
        for (int m = 1; m < 64; m <<= 1) {
            s += __shfl_xor(s, m);
            q += __shfl_xor(q, m);
        }
        float mean = s * (1.f / 128.f);
        float inv  = rsqrtf(q * (1.f / 128.f) - mean * mean + EPS);
        int row = r0 + ri;
        float2 o;
        o.x = (h0 - mean) * s0v * inv + o0v;
        o.y = (h1 - mean) * s1v * inv + o1v;
        *(float2*)&out[(size_t)row * 256 + 128 + cidx] = o;
    }
}

extern "C" void kernel_launch(void* const* d_in, const int* in_sizes, int n_in,
                              void* d_out, int out_size, void* d_ws, size_t ws_size,
                              hipStream_t stream)
{
    const float* feat = (const float*)d_in[0];
    const float* W0   = (const float*)d_in[1];
    const float* b0   = (const float*)d_in[2];
    const float* s0   = (const float*)d_in[3];
    const float* o0   = (const float*)d_in[4];
    const float* W1   = (const float*)d_in[5];
    const float* b1   = (const float*)d_in[6];
    const float* s1   = (const float*)d_in[7];
    const float* o1   = (const float*)d_in[8];
    const int*   er   = (const int*)d_in[9];
    const int*   ec   = (const int*)d_in[10];
    const float* ev   = (const float*)d_in[11];
    float* out = (float*)d_out;

    // workspace layout (16B-aligned offsets), total ~21.3 MB
    char*   wsb   = (char*)d_ws;
    ushort* Wb    = (ushort*)(wsb);                 //    131,072 B
    ushort* Y1    = (ushort*)(wsb + 131072);        // 12,800,000 B
    int*    gcnt  = (int*)   (wsb + 12931072);      //      3,128 B (padded 4K)
    uint2*  bedge = (uint2*) (wsb + 12935168);      //  8,408,064 B

    prep_small<<<1 + WB_BLOCKS, 256, 0, stream>>>(W0, W1, Wb, gcnt);

    gemm_scatter<<<SCATTER_BLOCKS + 2 * GEMM_MBLKS, 256, 0, stream>>>(
        feat, Wb, b0, s0, o0, out, Y1, er, ec, ev, gcnt, bedge);

    spmm_csr_ln<<<NBUCK, 512, 0, stream>>>(
        gcnt, bedge, Y1, b1, s1, o1, out);
}

// Round 4
// 175.426 us; speedup vs baseline: 4.7251x; 1.0213x over previous
//
#include <hip/hip_runtime.h>

#define N_NODES 50000
#define N_EDGES 800000
#define D_IN    256
#define D_OUT   128
#define EPS     1e-9f
#define BPAD    136     // Bs k-stride in ushorts: 272B rows (16B-aligned), 2-way bank alias = free

#define SCATTER_BLOCKS 196   // 196 * 4096 = 802816 >= 800000 edges
#define GEMM_MBLKS     391   // ceil(50000/128)

// bucket scatter: rows grouped 64/bucket; global atomics only per (block,bucket)
#define RPB    64
#define NBUCK  782           // ceil(50000/64)
#define BCAP   1344          // mean 1024 + 10 sigma; overflow ~impossible

typedef __attribute__((ext_vector_type(8))) short bf16x8;   // MFMA A/B frag (4 VGPRs)
typedef __attribute__((ext_vector_type(4))) float floatx4;  // MFMA C/D frag

__device__ __forceinline__ ushort f2bf(float x) {           // RTNE fp32 -> bf16
    unsigned u = __float_as_uint(x);
    u += 0x7fffu + ((u >> 16) & 1u);
    return (ushort)(u >> 16);
}

__device__ __forceinline__ bf16x8 packbf(float4 a, float4 b) {
    union { ushort us[8]; bf16x8 v; } r;
    r.us[0] = f2bf(a.x); r.us[1] = f2bf(a.y);
    r.us[2] = f2bf(a.z); r.us[3] = f2bf(a.w);
    r.us[4] = f2bf(b.x); r.us[5] = f2bf(b.y);
    r.us[6] = f2bf(b.z); r.us[7] = f2bf(b.w);
    return r.v;
}

// ---------------------------------------------------------------------------
// prep_small: (a) gcnt[NBUCK] = 0  (b) Wb[n][k] = bf16 transposed [W0|W1].
// ---------------------------------------------------------------------------
#define WB_BLOCKS  32
__global__ __launch_bounds__(256) void prep_small(
    const float* __restrict__ W0, const float* __restrict__ W1,
    ushort* __restrict__ Wb, int* __restrict__ gcnt)
{
    int bid = blockIdx.x;
    int t   = threadIdx.x;
    if (bid == 0) {
        for (int i = t; i < NBUCK; i += 256) gcnt[i] = 0;
    } else {
        int g  = (bid - 1) * 256 + t;
        int n  = g >> 5;                      // 0..255
        int kq = g & 31;                      // 8-elem k group
        const float* W = (n < 128) ? W0 : W1;
        int nn = n & 127;
        union { ushort us[8]; uint4 v; } tmp;
#pragma unroll
        for (int j = 0; j < 8; ++j)
            tmp.us[j] = f2bf(W[(size_t)(kq * 8 + j) * D_OUT + nn]);
        *(uint4*)&Wb[(size_t)n * D_IN + kq * 8] = tmp.v;
    }
}

// ---------------------------------------------------------------------------
// Fused kernel, BLOCK-role split, 512 threads.
//   bid < SCATTER_BLOCKS: LDS-aggregated bucket scatter of 4096 edges
//     (8/thread). LDS int atomics for ranks; one global atomicAdd per touched
//     (block,bucket) reserves a contiguous bedge range.
//   else: 128(M) x 128(N) gemm tile, 8 waves, each wave owns 16 rows.
//     A: global->register direct (feat rows are wave-private; zero A-reuse
//        across waves, so LDS staging of A was pure overhead + barriers).
//        8x float4 issued per K-phase, converted fp32->bf16 in-register.
//     B: LDS, staged in two K=128 phases (L2-hot Wb) -> 4 barriers/block.
//     half 0: cols 0..127  -> bias0+relu+LN -> out[:, 0:128]
//     half 1: cols 128..255 -> raw bf16 -> Y1[M,128]
// 16x16x32 layouts (HW-verified): A[m=lane&15][k=quad*8+j],
// B[k=quad*8+j][n=lane&15], D[row=quad*4+reg][col=lane&15].
// ---------------------------------------------------------------------------
__global__ __launch_bounds__(512, 4) void gemm_scatter(
    const float* __restrict__ feat, const ushort* __restrict__ Wb,
    const float* __restrict__ bias, const float* __restrict__ scale,
    const float* __restrict__ offset,
    float* __restrict__ out, ushort* __restrict__ Y1,
    const int* __restrict__ er, const int* __restrict__ ec,
    const float* __restrict__ ev, int* __restrict__ gcnt,
    uint2* __restrict__ bedge)
{
    __shared__ __align__(16) ushort Bs[128 * BPAD];   // 34816 B

    const int t = threadIdx.x;

    if (blockIdx.x < SCATTER_BLOCKS) {
        int* hist = (int*)Bs;          // NBUCK ints
        int* base = hist + NBUCK;      // NBUCK ints (6.3KB total, fits)
        for (int i = t; i < NBUCK; i += 512) hist[i] = 0;
        __syncthreads();

        int ebase = blockIdx.x * 4096;
        int   bkt[8], rnk[8];
        uint2 pk[8];
#pragma unroll
        for (int u = 0; u < 8; ++u) {
            int e = ebase + u * 512 + t;
            bool ok = (e < N_EDGES);
            int   r = ok ? er[e] : 0;
            int   c = ok ? ec[e] : 0;
            float v = ok ? ev[e] : 0.f;
            bkt[u] = ok ? (r >> 6) : -1;
            pk[u]  = make_uint2(((unsigned)(r & 63) << 16) | (unsigned)c,
                                __float_as_uint(v));
            if (ok) rnk[u] = atomicAdd(&hist[r >> 6], 1);   // LDS int atomic
        }
        __syncthreads();
        for (int i = t; i < NBUCK; i += 512) {
            int h = hist[i];
            base[i] = h ? atomicAdd(&gcnt[i], h) : 0;       // global atomic
        }
        __syncthreads();
#pragma unroll
        for (int u = 0; u < 8; ++u) {
            if (bkt[u] >= 0) {
                int pos = base[bkt[u]] + rnk[u];
                if (pos < BCAP)
                    bedge[(size_t)bkt[u] * BCAP + pos] = pk[u];
            }
        }
        return;
    }

    const int gbid = blockIdx.x - SCATTER_BLOCKS;       // 0..781
    const int half = gbid / GEMM_MBLKS;                 // 0 or 1
    const int mblk = gbid % GEMM_MBLKS;
    const int wave = t >> 6, lane = t & 63;
    const int quad = lane >> 4, l16 = lane & 15;
    const int m0   = mblk * 128;
    const int n0   = half * 128;

    const int grow = m0 + wave * 16 + l16;              // this lane's A row
    const int arow = grow < N_NODES ? grow : 0;         // clamp; results unused
    const float* aptr = &feat[(size_t)arow * D_IN + quad * 8];

    floatx4 acc[8];
#pragma unroll
    for (int nt = 0; nt < 8; ++nt)
        acc[nt] = (floatx4){0.f, 0.f, 0.f, 0.f};

    for (int kt = 0; kt < D_IN; kt += 128) {
        // ---- stage B (128 n-rows x 128 k) from L2-hot Wb[n][k] ----
#pragma unroll
        for (int i = 0; i < 8; ++i) {
            int g = t + i * 512;          // 0..4095
            int row = g >> 4, kq = g & 15;
            *(uint4*)&Bs[row * BPAD + kq * 8] =
                *(const uint4*)&Wb[(size_t)(n0 + row) * D_IN + kt + kq * 8];
        }
        __syncthreads();

        // ---- preload this phase's 4 A-frags (8 indep float4 in flight) ----
        const float* p = aptr + kt;
        float4 q0 = *(const float4*)(p +  0), q1 = *(const float4*)(p +  4);
        float4 q2 = *(const float4*)(p + 32), q3 = *(const float4*)(p + 36);
        float4 q4 = *(const float4*)(p + 64), q5 = *(const float4*)(p + 68);
        float4 q6 = *(const float4*)(p + 96), q7 = *(const float4*)(p + 100);
        bf16x8 a0 = packbf(q0, q1), a1 = packbf(q2, q3);
        bf16x8 a2 = packbf(q4, q5), a3 = packbf(q6, q7);

#pragma unroll
        for (int s = 0; s < 4; ++s) {
            bf16x8 a = (s == 0) ? a0 : (s == 1) ? a1 : (s == 2) ? a2 : a3;
            const int kk = s * 32;
            bf16x8 b[8];
#pragma unroll
            for (int nt = 0; nt < 8; ++nt)
                b[nt] = *(bf16x8*)&Bs[(nt * 16 + l16) * BPAD + kk + quad * 8];
#pragma unroll
            for (int nt = 0; nt < 8; ++nt)
                acc[nt] = __builtin_amdgcn_mfma_f32_16x16x32_bf16(
                    a, b[nt], acc[nt], 0, 0, 0);
        }
        __syncthreads();
    }

    if (half == 0) {
        float bb[8], sc[8], of[8];
#pragma unroll
        for (int nt = 0; nt < 8; ++nt) {
            bb[nt] = bias[nt * 16 + l16];
            sc[nt] = scale[nt * 16 + l16];
            of[nt] = offset[nt * 16 + l16];
        }
#pragma unroll
        for (int i = 0; i < 4; ++i) {
            float h[8], s = 0.f, q = 0.f;
#pragma unroll
            for (int nt = 0; nt < 8; ++nt) {
                h[nt] = fmaxf(acc[nt][i] + bb[nt], 0.f);
                s += h[nt];
                q += h[nt] * h[nt];
            }
#pragma unroll
            for (int m = 1; m < 16; m <<= 1) {
                s += __shfl_xor(s, m);
                q += __shfl_xor(q, m);
            }
            float mean = s * (1.f / 128.f);
            float inv  = rsqrtf(q * (1.f / 128.f) - mean * mean + EPS);
            int row = m0 + wave * 16 + quad * 4 + i;
            if (row < N_NODES) {
#pragma unroll
                for (int nt = 0; nt < 8; ++nt)
                    out[(size_t)row * 256 + nt * 16 + l16] =
                        (h[nt] - mean) * sc[nt] * inv + of[nt];
            }
        }
    } else {
#pragma unroll
        for (int i = 0; i < 4; ++i) {
            int row = m0 + wave * 16 + quad * 4 + i;
            if (row < N_NODES) {
#pragma unroll
                for (int nt = 0; nt < 8; ++nt)
                    Y1[(size_t)row * D_OUT + nt * 16 + l16] =
                        f2bf(acc[nt][i]);
            }
        }
    }
}

// ---------------------------------------------------------------------------
// One block per bucket (64 rows, ~1024 edges), 512 threads (8 waves).
// ONE-pass CSR build: each thread keeps <=3 edges in NAMED registers
// (no runtime-indexed arrays -> no scratch), LDS int atomics give per-row
// ranks, wave 0 does a 64-wide shfl prefix scan, place from registers.
// Then wave-per-row gather of bf16 Y rows (8-deep ILP) + bias+relu+LN
// -> out[:, 128:256].
// LDS ~8.6KB; 782 blocks -> ~3 blocks/CU x 8 waves = 24 waves/CU.
// ---------------------------------------------------------------------------
__global__ __launch_bounds__(512) void spmm_csr_ln(
    const int* __restrict__ gcnt, const uint2* __restrict__ bedge,
    const ushort* __restrict__ Y,
    const float* __restrict__ bias, const float* __restrict__ scale,
    const float* __restrict__ offset, float* __restrict__ out)
{
    __shared__ ushort lcol[BCAP];
    __shared__ float  lval[BCAP];
    __shared__ int    cnt[RPB];
    __shared__ int    offx[RPB];

    const int t      = threadIdx.x;
    const int bucket = blockIdx.x;
    const int r0     = bucket * RPB;
    const int nrows  = min(RPB, N_NODES - r0);
    int ne = gcnt[bucket];
    ne = ne < BCAP ? ne : BCAP;

    if (t < RPB) cnt[t] = 0;
    __syncthreads();

    // ---- count pass (single bedge read; edges parked in named regs) ----
    const size_t base = (size_t)bucket * BCAP;
    int   erA = -1, erB = -1, erC = -1;
    int   ecA = 0,  ecB = 0,  ecC = 0;
    float evA = 0.f, evB = 0.f, evC = 0.f;
    int   rkA = 0,  rkB = 0,  rkC = 0;
    if (t < ne) {
        uint2 p = bedge[base + t];
        erA = (int)(p.x >> 16); ecA = (int)(p.x & 0xffffu);
        evA = __uint_as_float(p.y);
        rkA = atomicAdd(&cnt[erA], 1);
    }
    if (t + 512 < ne) {
        uint2 p = bedge[base + t + 512];
        erB = (int)(p.x >> 16); ecB = (int)(p.x & 0xffffu);
        evB = __uint_as_float(p.y);
        rkB = atomicAdd(&cnt[erB], 1);
    }
    if (t + 1024 < ne) {
        uint2 p = bedge[base + t + 1024];
        erC = (int)(p.x >> 16); ecC = (int)(p.x & 0xffffu);
        evC = __uint_as_float(p.y);
        rkC = atomicAdd(&cnt[erC], 1);
    }
    __syncthreads();

    // ---- exclusive prefix over 64 counts, wave 0 via shfl ----
    if (t < RPB) {
        int c = cnt[t], x = c;
#pragma unroll
        for (int s = 1; s < RPB; s <<= 1) {
            int w = __shfl_up(x, s);
            if (t >= s) x += w;
        }
        offx[t] = x - c;
    }
    __syncthreads();

    // ---- place from registers ----
    if (erA >= 0) { int k = offx[erA] + rkA; lcol[k] = (ushort)ecA; lval[k] = evA; }
    if (erB >= 0) { int k = offx[erB] + rkB; lcol[k] = (ushort)ecB; lval[k] = evB; }
    if (erC >= 0) { int k = offx[erC] + rkC; lcol[k] = (ushort)ecC; lval[k] = evC; }
    __syncthreads();

    // ---- wave-per-row gather + LN ----
    const int wave = t >> 6, lane = t & 63;
    const int cidx = lane * 2;
    const float b0v = bias[cidx],   b1v = bias[cidx + 1];
    const float s0v = scale[cidx],  s1v = scale[cidx + 1];
    const float o0v = offset[cidx], o1v = offset[cidx + 1];

    for (int ri = wave; ri < nrows; ri += 8) {
        int beg = offx[ri], n = cnt[ri];
        float ax = 0.f, ay = 0.f;
        int j = 0;
        for (; j + 8 <= n; j += 8) {
            unsigned yv[8]; float vv[8]; int cc[8];
#pragma unroll
            for (int u = 0; u < 8; ++u) {
                cc[u] = lcol[beg + j + u];             // LDS broadcast
                vv[u] = lval[beg + j + u];
                yv[u] = *(const unsigned*)&Y[(size_t)cc[u] * D_OUT + cidx];
            }
#pragma unroll
            for (int u = 0; u < 8; ++u) {
                ax = fmaf(vv[u], __uint_as_float(yv[u] << 16), ax);
                ay = fmaf(vv[u], __uint_as_float(yv[u] & 0xffff0000u), ay);
            }
        }
        for (; j < n; ++j) {
            int   c  = lcol[beg + j];
            float vj = lval[beg + j];
            unsigned yv = *(const unsigned*)&Y[(size_t)c * D_OUT + cidx];
            ax = fmaf(vj, __uint_as_float(yv << 16), ax);
            ay = fmaf(vj, __uint_as_float(yv & 0xffff0000u), ay);
        }
        float h0 = fmaxf(ax + b0v, 0.f);
        float h1 = fmaxf(ay + b1v, 0.f);
        float s = h0 + h1, q = h0 * h0 + h1 * h1;
#pragma unroll
        for (int m = 1; m < 64; m <<= 1) {
            s += __shfl_xor(s, m);
            q += __shfl_xor(q, m);
        }
        float mean = s * (1.f / 128.f);
        float inv  = rsqrtf(q * (1.f / 128.f) - mean * mean + EPS);
        int row = r0 + ri;
        float2 o;
        o.x = (h0 - mean) * s0v * inv + o0v;
        o.y = (h1 - mean) * s1v * inv + o1v;
        *(float2*)&out[(size_t)row * 256 + 128 + cidx] = o;
    }
}

extern "C" void kernel_launch(void* const* d_in, const int* in_sizes, int n_in,
                              void* d_out, int out_size, void* d_ws, size_t ws_size,
                              hipStream_t stream)
{
    const float* feat = (const float*)d_in[0];
    const float* W0   = (const float*)d_in[1];
    const float* b0   = (const float*)d_in[2];
    const float* s0   = (const float*)d_in[3];
    const float* o0   = (const float*)d_in[4];
    const float* W1   = (const float*)d_in[5];
    const float* b1   = (const float*)d_in[6];
    const float* s1   = (const float*)d_in[7];
    const float* o1   = (const float*)d_in[8];
    const int*   er   = (const int*)d_in[9];
    const int*   ec   = (const int*)d_in[10];
    const float* ev   = (const float*)d_in[11];
    float* out = (float*)d_out;

    // workspace layout (16B-aligned offsets), total ~21.3 MB
    char*   wsb   = (char*)d_ws;
    ushort* Wb    = (ushort*)(wsb);                 //    131,072 B
    ushort* Y1    = (ushort*)(wsb + 131072);        // 12,800,000 B
    int*    gcnt  = (int*)   (wsb + 12931072);      //      3,128 B (padded 4K)
    uint2*  bedge = (uint2*) (wsb + 12935168);      //  8,408,064 B

    prep_small<<<1 + WB_BLOCKS, 256, 0, stream>>>(W0, W1, Wb, gcnt);

    gemm_scatter<<<SCATTER_BLOCKS + 2 * GEMM_MBLKS, 512, 0, stream>>>(
        feat, Wb, b0, s0, o0, out, Y1, er, ec, ev, gcnt, bedge);

    spmm_csr_ln<<<NBUCK, 512, 0, stream>>>(
        gcnt, bedge, Y1, b1, s1, o1, out);
}